// Round 1
// baseline (385.321 us; speedup 1.0000x reference)
//
#include <hip/hip_runtime.h>
#include <hip/hip_bf16.h>

// ProtoLayer: dists_to_protos[n][p] = |f_n|^2 + |p_p|^2 - 2 f_n.p_p  (N x P)
//             dists_to_latents      = transpose of the above          (P x N)
// N=65536, P=512, D=256, fp32 in/out. Memory-bound (~332 MB traffic, floor ~53us).
// R4: barrier-free restructure. Previous version staged A in LDS behind two
//     __syncthreads with 2 blocks/CU resident -> phase-serialized (loads and
//     the 256 MiB store burst never overlap). Now each wave loads its MFMA
//     A-fragment directly from global (L2 absorbs the 4x intra-block re-read),
//     converts fp32->bf16 in-register, computes fsq via in-reg accumulation +
//     shuffles. Epilogue transpose tiles are per-wave private => ZERO barriers.
//     Blocks: 256 threads / 32 feature rows (2048 blocks) for finer scheduling.

#define DD 256
#define PP 512
#define BN 32
#define TP 36   // transpose tile pad: 32+4 keeps 16B alignment for b128 ops

typedef short bf16x8 __attribute__((ext_vector_type(8)));
typedef float f32x16 __attribute__((ext_vector_type(16)));
typedef float f32x4 __attribute__((ext_vector_type(4)));
typedef unsigned short u16x4 __attribute__((ext_vector_type(4)));

__device__ __forceinline__ unsigned short f2bf(float f) {
    unsigned int u = __builtin_bit_cast(unsigned int, f);
    u = (u + 0x7fffu + ((u >> 16) & 1u)) >> 16;   // RNE
    return (unsigned short)u;
}

// --- prep: prototypes fp32 -> bf16 (row-major [P][D]) + proto_sq fp32 ---
__global__ __launch_bounds__(256) void proto_prep(const float* __restrict__ proto,
                                                  unsigned short* __restrict__ bw,
                                                  float* __restrict__ psq) {
    const int w = threadIdx.x >> 6, lane = threadIdx.x & 63;
    const int row = blockIdx.x * 4 + w;                 // 128 blocks * 4 rows
    const f32x4 f = *(const f32x4*)(proto + (size_t)row * DD + lane * 4);
    u16x4 u;
    u.x = f2bf(f.x); u.y = f2bf(f.y); u.z = f2bf(f.z); u.w = f2bf(f.w);
    *(u16x4*)(bw + (size_t)row * DD + lane * 4) = u;
    float part = f.x * f.x + f.y * f.y + f.z * f.z + f.w * f.w;
    for (int o = 32; o > 0; o >>= 1) part += __shfl_xor(part, o, 64);
    if (lane == 0) psq[row] = part;
}

// --- main: block = 4 waves, 32 feature rows x all 512 prototypes, no barriers ---
__global__ __launch_bounds__(256, 4) void proto_dist(
        const float* __restrict__ feat,
        const unsigned short* __restrict__ bw,
        const float* __restrict__ psq,
        float* __restrict__ out0,   // [N][512]
        float* __restrict__ out1,   // [512][N]
        int N) {
    // per-wave private 32x36 fp32 transpose tiles; no cross-wave sharing
    __shared__ float S[4 * 32 * TP];                    // 18432 B

    const int tid = threadIdx.x;
    const int w = tid >> 6, lane = tid & 63;
    const int n0 = blockIdx.x * BN;
    const int colbase = w * 128;                        // wave = one p-group
    const int l31 = lane & 31;
    const int hi = lane >> 5;

    // A operand straight from global: A[m = lane&31][k = (lane>>5)*8 + j]
    const float* arow = feat + (size_t)(n0 + l31) * DD + hi * 8;
    // B operand: B[n = lane&31][k = (lane>>5)*8 + j], protos row-major, L2-hot
    const unsigned short* bbase = bw + (size_t)(colbase + l31) * DD + hi * 8;

    f32x16 acc[4];
    #pragma unroll
    for (int t = 0; t < 4; ++t)
        #pragma unroll
        for (int e = 0; e < 16; ++e) acc[t][e] = 0.0f;

    float part = 0.0f;   // running sum of squares over this lane's k-half

    #pragma unroll 2
    for (int k0 = 0; k0 < DD; k0 += 16) {
        const f32x4 f0 = *(const f32x4*)(arow + k0);
        const f32x4 f1 = *(const f32x4*)(arow + k0 + 4);
        bf16x8 a;
        a[0] = (short)f2bf(f0.x); a[1] = (short)f2bf(f0.y);
        a[2] = (short)f2bf(f0.z); a[3] = (short)f2bf(f0.w);
        a[4] = (short)f2bf(f1.x); a[5] = (short)f2bf(f1.y);
        a[6] = (short)f2bf(f1.z); a[7] = (short)f2bf(f1.w);
        part += f0.x * f0.x + f0.y * f0.y + f0.z * f0.z + f0.w * f0.w
              + f1.x * f1.x + f1.y * f1.y + f1.z * f1.z + f1.w * f1.w;
        #pragma unroll
        for (int t = 0; t < 4; ++t) {
            const bf16x8 b = *(const bf16x8*)(bbase + (size_t)(32 * t) * DD + k0);
            acc[t] = __builtin_amdgcn_mfma_f32_32x32x16_bf16(a, b, acc[t], 0, 0, 0);
        }
    }

    // fsq[m]: lane m holds k-half hi=0, lane m+32 holds hi=1; combine + spread
    part += __shfl_xor(part, 32, 64);
    float fsq_q[4][4];
    #pragma unroll
    for (int q = 0; q < 4; ++q)
        #pragma unroll
        for (int e = 0; e < 4; ++e)
            fsq_q[q][e] = __shfl(part, e + 8 * q + 4 * hi, 64);

    float* trans = S + w * (32 * TP);   // per-wave 32x36 fp32
    float* out0_base = out0 + (size_t)n0 * PP;

    #pragma unroll
    for (int t = 0; t < 4; ++t) {
        const int p = colbase + 32 * t + l31;
        const float psq_v = psq[p];
        // C/D layout (m74/m101): col = lane&31, row = (reg&3)+8*(reg>>2)+4*(lane>>5)
        #pragma unroll
        for (int q = 0; q < 4; ++q) {
            f32x4 d;
            #pragma unroll
            for (int e = 0; e < 4; ++e) {
                const int reg = 4 * q + e;
                const int n_l = e + 8 * q + 4 * hi;
                const float dist = fsq_q[q][e] + psq_v - 2.0f * acc[t][reg];
                d[e] = dist;
                __builtin_nontemporal_store(dist, out0_base + (size_t)n_l * PP + p);
            }
            // p-major transpose tile: row = p-local (l31), 4 consecutive n
            *(f32x4*)&trans[l31 * TP + 8 * q + 4 * hi] = d;
        }
        // same-wave LDS exchange (in-order DS per wave, compiler inserts lgkmcnt)
        #pragma unroll
        for (int j = 0; j < 4; ++j) {
            const int p_row = j * 8 + (lane >> 3);       // 8 p-rows per instr
            const int n_off = (lane & 7) * 4;            // 8 lanes * 4 n = 32 n
            const f32x4 v = *(const f32x4*)&trans[p_row * TP + n_off];
            __builtin_nontemporal_store(v,
                (f32x4*)(out1 + (size_t)(colbase + 32 * t + p_row) * N
                               + (n0 + n_off)));
        }
    }
}

extern "C" void kernel_launch(void* const* d_in, const int* in_sizes, int n_in,
                              void* d_out, int out_size, void* d_ws, size_t ws_size,
                              hipStream_t stream) {
    const float* feat = (const float*)d_in[0];
    const float* proto = (const float*)d_in[1];
    const int N = in_sizes[0] / DD;          // 65536

    unsigned short* bw = (unsigned short*)d_ws;                // 512*256*2 = 256 KB
    float* psq = (float*)((char*)d_ws + (size_t)PP * DD * 2);  // +2 KB

    float* out0 = (float*)d_out;
    float* out1 = out0 + (size_t)N * PP;

    proto_prep<<<PP / 4, 256, 0, stream>>>(proto, bw, psq);
    proto_dist<<<N / BN, 256, 0, stream>>>(feat, bw, psq, out0, out1, N);
}

// Round 2
// 376.044 us; speedup vs baseline: 1.0247x; 1.0247x over previous
//
#include <hip/hip_runtime.h>
#include <hip/hip_bf16.h>

// ProtoLayer: dists_to_protos[n][p] = |f_n|^2 + |p_p|^2 - 2 f_n.p_p  (N x P)
//             dists_to_latents      = transpose of the above          (P x N)
// N=65536, P=512, D=256, fp32 in/out. Memory-bound (~332 MB traffic, floor ~53us).
// R5: back to coalesced LDS staging (R4's direct-global A was a 64-line/instr
//     gather -> +28us). Structural changes vs R3:
//     - dual MFMA (acc=mfma(a,b), acc2=mfma(b,a)): acc2 rows=p, cols=n gives
//       out1 lanes n-contiguous => no LDS transpose, no 2nd barrier, and both
//       outputs store as 2x128B merged segments per scalar-store instr.
//     - per-t (32-proto) compute+store slices: stores spread through kernel,
//       acc live range 32 regs instead of 64.
//     - 256-thread/32-row blocks, LDS=A-slab only (17.9KB), 1 barrier,
//       launch_bounds(256,4) -> ~4 blocks/CU (R3 had 2): load/store streams mix.
//     - A-slab row stride 280 bf16 (dword-stride 140 === 12 mod 32): the
//       lane-strided ds_read_b128 A-reads tile all 32 banks (R3's 264 was 4-way).

#define DD 256
#define PP 512
#define BN 32
#define AP 280   // A slab row stride in bf16 elems (256 + 24 pad)

typedef short bf16x8 __attribute__((ext_vector_type(8)));
typedef float f32x16 __attribute__((ext_vector_type(16)));
typedef float f32x4 __attribute__((ext_vector_type(4)));
typedef unsigned short u16x4 __attribute__((ext_vector_type(4)));

__device__ __forceinline__ unsigned short f2bf(float f) {
    unsigned int u = __builtin_bit_cast(unsigned int, f);
    u = (u + 0x7fffu + ((u >> 16) & 1u)) >> 16;   // RNE
    return (unsigned short)u;
}

// --- prep: prototypes fp32 -> bf16 (row-major [P][D]) + proto_sq fp32 ---
__global__ __launch_bounds__(256) void proto_prep(const float* __restrict__ proto,
                                                  unsigned short* __restrict__ bw,
                                                  float* __restrict__ psq) {
    const int w = threadIdx.x >> 6, lane = threadIdx.x & 63;
    const int row = blockIdx.x * 4 + w;                 // 128 blocks * 4 rows
    const f32x4 f = *(const f32x4*)(proto + (size_t)row * DD + lane * 4);
    u16x4 u;
    u.x = f2bf(f.x); u.y = f2bf(f.y); u.z = f2bf(f.z); u.w = f2bf(f.w);
    *(u16x4*)(bw + (size_t)row * DD + lane * 4) = u;
    float part = f.x * f.x + f.y * f.y + f.z * f.z + f.w * f.w;
    for (int o = 32; o > 0; o >>= 1) part += __shfl_xor(part, o, 64);
    if (lane == 0) psq[row] = part;
}

// --- main: block = 4 waves, 32 feature rows x all 512 prototypes ---
__global__ __launch_bounds__(256, 4) void proto_dist(
        const float* __restrict__ feat,
        const unsigned short* __restrict__ bw,
        const float* __restrict__ psq,
        float* __restrict__ out0,   // [N][512]
        float* __restrict__ out1,   // [512][N]
        int N) {
    __shared__ unsigned short A_lds[BN * AP];           // 17920 B
    __shared__ float fsq[BN];

    const int tid = threadIdx.x;
    const int w = tid >> 6, lane = tid & 63;
    const int n0 = blockIdx.x * BN;

    // stage A: fp32 global -> bf16 LDS (coalesced; feat read exactly once)
    #pragma unroll
    for (int i = 0; i < 8; ++i) {
        const int row = i * 4 + w;
        const f32x4 f = __builtin_nontemporal_load(
            (const f32x4*)(feat + (size_t)(n0 + row) * DD + lane * 4));
        u16x4 u;
        u.x = f2bf(f.x); u.y = f2bf(f.y); u.z = f2bf(f.z); u.w = f2bf(f.w);
        *(u16x4*)&A_lds[row * AP + lane * 4] = u;
        float part = f.x * f.x + f.y * f.y + f.z * f.z + f.w * f.w;
        for (int o = 32; o > 0; o >>= 1) part += __shfl_xor(part, o, 64);
        if (lane == 0) fsq[row] = part;
    }
    __syncthreads();   // the only barrier

    const int l31 = lane & 31;
    const int hi = lane >> 5;
    const int colT = w * 128;                           // wave = one p-group

    // A operand: A[m = lane&31][k = (lane>>5)*8 + j]
    const unsigned short* arow = &A_lds[l31 * AP + hi * 8];

    // fsq broadcast quads: fsq[e + 8q + 4hi] for out0's reg-rows
    f32x4 fsq_q[4];
    #pragma unroll
    for (int q = 0; q < 4; ++q)
        fsq_q[q] = *(const f32x4*)&fsq[8 * q + 4 * hi];
    const float fsq_lane = fsq[l31];                    // out1's lane-col n

    #pragma unroll
    for (int t = 0; t < 4; ++t) {
        const int pbase = colT + 32 * t;
        // B operand: B[n = lane&31][k = (lane>>5)*8 + j], protos row-major, L2-hot
        const unsigned short* bb = bw + (size_t)(pbase + l31) * DD + hi * 8;

        f32x16 acc, acc2;
        #pragma unroll
        for (int e = 0; e < 16; ++e) { acc[e] = 0.0f; acc2[e] = 0.0f; }

        #pragma unroll 4
        for (int k0 = 0; k0 < DD; k0 += 16) {
            const bf16x8 a = *(const bf16x8*)(arow + k0);
            const bf16x8 b = *(const bf16x8*)(bb + k0);
            acc  = __builtin_amdgcn_mfma_f32_32x32x16_bf16(a, b, acc,  0, 0, 0);
            acc2 = __builtin_amdgcn_mfma_f32_32x32x16_bf16(b, a, acc2, 0, 0, 0);
        }

        // out0 from acc: D[row=n (reg), col=p (lane)]; lanes p-contiguous.
        // C/D layout (m74/m101): col = lane&31, row = (reg&3)+8*(reg>>2)+4*(lane>>5)
        const float psq_lane = psq[pbase + l31];
        float* o0 = out0 + (size_t)n0 * PP + pbase + l31;
        #pragma unroll
        for (int q = 0; q < 4; ++q) {
            #pragma unroll
            for (int e = 0; e < 4; ++e) {
                const int n_l = e + 8 * q + 4 * hi;
                const float dist = fsq_q[q][e] + psq_lane - 2.0f * acc[4 * q + e];
                __builtin_nontemporal_store(dist, o0 + (size_t)n_l * PP);
            }
        }

        // out1 from acc2: D2[row=p (reg), col=n (lane)]; lanes n-contiguous.
        float* o1 = out1 + (size_t)pbase * N + n0 + l31;
        #pragma unroll
        for (int q = 0; q < 4; ++q) {
            const f32x4 ps4 = *(const f32x4*)(psq + pbase + 8 * q + 4 * hi);
            #pragma unroll
            for (int e = 0; e < 4; ++e) {
                const int p_l = e + 8 * q + 4 * hi;
                const float dist = fsq_lane + ps4[e] - 2.0f * acc2[4 * q + e];
                __builtin_nontemporal_store(dist, o1 + (size_t)p_l * N);
            }
        }
    }
}

extern "C" void kernel_launch(void* const* d_in, const int* in_sizes, int n_in,
                              void* d_out, int out_size, void* d_ws, size_t ws_size,
                              hipStream_t stream) {
    const float* feat = (const float*)d_in[0];
    const float* proto = (const float*)d_in[1];
    const int N = in_sizes[0] / DD;          // 65536

    unsigned short* bw = (unsigned short*)d_ws;                // 512*256*2 = 256 KB
    float* psq = (float*)((char*)d_ws + (size_t)PP * DD * 2);  // +2 KB

    float* out0 = (float*)d_out;
    float* out1 = out0 + (size_t)N * PP;

    proto_prep<<<PP / 4, 256, 0, stream>>>(proto, bw, psq);
    proto_dist<<<N / BN, 256, 0, stream>>>(feat, bw, psq, out0, out1, N);
}

// Round 3
// 359.177 us; speedup vs baseline: 1.0728x; 1.0470x over previous
//
#include <hip/hip_runtime.h>
#include <hip/hip_bf16.h>

// ProtoLayer: dists_to_protos[n][p] = |f_n|^2 + |p_p|^2 - 2 f_n.p_p  (N x P)
//             dists_to_latents      = transpose of the above          (P x N)
// N=65536, P=512, D=256, fp32 in/out. Memory-bound (~332 MB traffic, floor ~53us).
// R6: write-run-length restructure. R3/R4/R5 all stored 128B segments at 2KB /
//     256KB strides and all landed at dist ~190-215us (~1.7 TB/s effective);
//     the harness's own fillBuffer streams contiguous writes at 6.4 TB/s.
//     Fix: cooperative LDS assembly epilogue.
//       out0: two [32 n][512 p] fp32 slices; readback stores 1KB contiguous
//             per instruction (64 lanes x f32x4), full 2KB rows per 2 instrs.
//       out1: four [128 p][64 n] slices (n-stride 68 dwords); readback stores
//             256B runs (2x previous). ds_write_b128 assembly is bank-optimal.
//     Compute core = R3 shape (single MFMA, acc[4], coalesced bf16 staging)
//     with AP=280 (dword-stride === 12 mod 32 -> conflict-free A ds_read_b128).

#define DD 256
#define PP 512
#define BN 64
#define AP 280   // A slab row stride in bf16 elems (256 + 24 pad)
#define O1S 68   // out1 slice n-stride in dwords (64 + 4 pad)

typedef short bf16x8 __attribute__((ext_vector_type(8)));
typedef float f32x16 __attribute__((ext_vector_type(16)));
typedef float f32x4 __attribute__((ext_vector_type(4)));
typedef unsigned short u16x4 __attribute__((ext_vector_type(4)));

__device__ __forceinline__ unsigned short f2bf(float f) {
    unsigned int u = __builtin_bit_cast(unsigned int, f);
    u = (u + 0x7fffu + ((u >> 16) & 1u)) >> 16;   // RNE
    return (unsigned short)u;
}

// --- prep: prototypes fp32 -> bf16 (row-major [P][D]) + proto_sq fp32 ---
__global__ __launch_bounds__(256) void proto_prep(const float* __restrict__ proto,
                                                  unsigned short* __restrict__ bw,
                                                  float* __restrict__ psq) {
    const int w = threadIdx.x >> 6, lane = threadIdx.x & 63;
    const int row = blockIdx.x * 4 + w;                 // 128 blocks * 4 rows
    const f32x4 f = *(const f32x4*)(proto + (size_t)row * DD + lane * 4);
    u16x4 u;
    u.x = f2bf(f.x); u.y = f2bf(f.y); u.z = f2bf(f.z); u.w = f2bf(f.w);
    *(u16x4*)(bw + (size_t)row * DD + lane * 4) = u;
    float part = f.x * f.x + f.y * f.y + f.z * f.z + f.w * f.w;
    for (int o = 32; o > 0; o >>= 1) part += __shfl_xor(part, o, 64);
    if (lane == 0) psq[row] = part;
}

// --- main: block = 8 waves, 64 feature rows x all 512 prototypes ---
__global__ __launch_bounds__(512, 4) void proto_dist(
        const float* __restrict__ feat,
        const unsigned short* __restrict__ bw,
        const float* __restrict__ psq,
        float* __restrict__ out0,   // [N][512]
        float* __restrict__ out1,   // [512][N]
        int N) {
    // union region: phase 1 A-slab 64x280 bf16 (35840B);
    //               phase 2 out0 slice [32][512] f32 (65536B)  <- max
    //               phase 3 out1 slice [128][68] f32 (34816B)
    __shared__ unsigned char S[65536];
    __shared__ float fsq[BN];
    unsigned short* A_lds = (unsigned short*)S;
    float* lds_f = (float*)S;

    const int tid = threadIdx.x;
    const int w = tid >> 6, lane = tid & 63;
    const int n0 = blockIdx.x * BN;

    // stage A: fp32 global -> bf16 LDS (coalesced; feat read exactly once)
    #pragma unroll
    for (int i = 0; i < 8; ++i) {
        const int row = i * 8 + w;
        const f32x4 f = __builtin_nontemporal_load(
            (const f32x4*)(feat + (size_t)(n0 + row) * DD + lane * 4));
        u16x4 u;
        u.x = f2bf(f.x); u.y = f2bf(f.y); u.z = f2bf(f.z); u.w = f2bf(f.w);
        *(u16x4*)&A_lds[row * AP + lane * 4] = u;
        float part = f.x * f.x + f.y * f.y + f.z * f.z + f.w * f.w;
        for (int o = 32; o > 0; o >>= 1) part += __shfl_xor(part, o, 64);
        if (lane == 0) fsq[row] = part;
    }
    __syncthreads();

    const int r = w & 1;            // n-tile (32 rows)
    const int g = w >> 1;           // p-group (128 cols)
    const int colT = g * 128;
    const int l31 = lane & 31;
    const int hi = lane >> 5;

    // A operand: A[m = lane&31][k = (lane>>5)*8 + j]
    const unsigned short* arow = &A_lds[(32 * r + l31) * AP + hi * 8];

    f32x16 acc[4];
    #pragma unroll
    for (int t = 0; t < 4; ++t)
        #pragma unroll
        for (int e = 0; e < 16; ++e) acc[t][e] = 0.0f;

    #pragma unroll 2
    for (int k0 = 0; k0 < DD; k0 += 16) {
        const bf16x8 a = *(const bf16x8*)(arow + k0);
        #pragma unroll
        for (int t = 0; t < 4; ++t) {
            const bf16x8 b = *(const bf16x8*)(
                bw + (size_t)(colT + 32 * t + l31) * DD + hi * 8 + k0);
            acc[t] = __builtin_amdgcn_mfma_f32_32x32x16_bf16(a, b, acc[t], 0, 0, 0);
        }
    }

    // per-lane epilogue constants (fsq is its own LDS array, safe to read)
    f32x4 fsq_q[4];
    #pragma unroll
    for (int q = 0; q < 4; ++q)
        fsq_q[q] = *(const f32x4*)&fsq[32 * r + 8 * q + 4 * hi];
    f32x4 psqv;
    #pragma unroll
    for (int t = 0; t < 4; ++t) psqv[t] = psq[colT + 32 * t + l31];

    __syncthreads();   // all waves done reading A_lds; reuse region

    // ---- out0: two slices of [32 n][512 p], stores 1KB/instr ----
    #pragma unroll
    for (int s = 0; s < 2; ++s) {
        if (r == s) {
            // C/D layout (m74/m101): col=lane&31 (p), row=(reg&3)+8*(reg>>2)+4*hi (n)
            #pragma unroll
            for (int t = 0; t < 4; ++t)
                #pragma unroll
                for (int q = 0; q < 4; ++q)
                    #pragma unroll
                    for (int e = 0; e < 4; ++e) {
                        const int n_l = e + 8 * q + 4 * hi;
                        lds_f[n_l * 512 + colT + 32 * t + l31] =
                            fsq_q[q][e] + psqv[t] - 2.0f * acc[t][4 * q + e];
                    }
        }
        __syncthreads();
        float* o0 = out0 + (size_t)(n0 + 32 * s) * PP;
        const int row = tid >> 7;              // 0..3
        const int off = (tid & 127) * 4;       // 0..508
        #pragma unroll
        for (int rr = 0; rr < 8; ++rr) {
            const f32x4 v = *(const f32x4*)&lds_f[(row + 4 * rr) * 512 + off];
            __builtin_nontemporal_store(
                v, (f32x4*)(o0 + (size_t)(row + 4 * rr) * PP + off));
        }
        __syncthreads();
    }

    // ---- out1: four slices of [128 p][64 n] (stride 68), stores 256B runs ----
    #pragma unroll
    for (int sp = 0; sp < 4; ++sp) {
        if (g == sp) {
            #pragma unroll
            for (int t = 0; t < 4; ++t) {
                const int p_loc = 32 * t + l31;
                #pragma unroll
                for (int q = 0; q < 4; ++q) {
                    f32x4 d;
                    #pragma unroll
                    for (int e = 0; e < 4; ++e)
                        d[e] = fsq_q[q][e] + psqv[t] - 2.0f * acc[t][4 * q + e];
                    // n = 32r + e+8q+4hi: quad over e is 4 consecutive n
                    *(f32x4*)&lds_f[p_loc * O1S + 32 * r + 8 * q + 4 * hi] = d;
                }
            }
        }
        __syncthreads();
        const int p_row = tid >> 4;            // 0..31
        const int n_off = (tid & 15) * 4;      // 0..60
        float* o1 = out1 + (size_t)(128 * sp) * N + n0;
        #pragma unroll
        for (int rr = 0; rr < 4; ++rr) {
            const f32x4 v = *(const f32x4*)&lds_f[(p_row + 32 * rr) * O1S + n_off];
            __builtin_nontemporal_store(
                v, (f32x4*)(o1 + (size_t)(p_row + 32 * rr) * N + n_off));
        }
        if (sp < 3) __syncthreads();
    }
}

extern "C" void kernel_launch(void* const* d_in, const int* in_sizes, int n_in,
                              void* d_out, int out_size, void* d_ws, size_t ws_size,
                              hipStream_t stream) {
    const float* feat = (const float*)d_in[0];
    const float* proto = (const float*)d_in[1];
    const int N = in_sizes[0] / DD;          // 65536

    unsigned short* bw = (unsigned short*)d_ws;                // 512*256*2 = 256 KB
    float* psq = (float*)((char*)d_ws + (size_t)PP * DD * 2);  // +2 KB

    float* out0 = (float*)d_out;
    float* out1 = out0 + (size_t)N * PP;

    proto_prep<<<PP / 4, 256, 0, stream>>>(proto, bw, psq);
    proto_dist<<<N / BN, 512, 0, stream>>>(feat, bw, psq, out0, out1, N);
}

// Round 6
// 326.608 us; speedup vs baseline: 1.1798x; 1.0997x over previous
//
#include <hip/hip_runtime.h>
#include <hip/hip_bf16.h>

// ProtoLayer: dists_to_protos[n][p] = |f_n|^2 + |p_p|^2 - 2 f_n.p_p  (N x P)
//             dists_to_latents      = transpose of the above          (P x N)
// N=65536, P=512, D=256, fp32 in/out. Memory-bound (~332 MB traffic, floor ~53us).
// R7b (third submit; two prior runs died to container-level failures with no
//     compile/test error; source audited clean: no divergent barriers, no OOB,
//     aligned vector ops. Perturbed codegen: K-loop unroll 4 -> 2 to match the
//     proven R6 path and force a fresh compile cache entry.)
//     Experiment: pre-swizzled B fragments. Evidence: R3==R6 (store geometry
//     irrelevant), R4 +28us (added gather load stream), R5 +15us (more K-loop
//     VMEM issue) => K-loop VMEM service is the limiter. Old B-load gathered 32
//     sectors/instr (lanes stride 512B). proto_prep now emits bw in MFMA
//     fragment order [tile p/32][kk][lane][8]: each dist B-load is 64 lanes x
//     16B CONTIGUOUS (one 1KB transaction), pure streaming, every line consumed
//     once. A-path (LDS AP=280 conflict-free) and R6 epilogue unchanged.

#define DD 256
#define PP 512
#define BN 64
#define AP 280   // A slab row stride in bf16 elems (256 + 24 pad)
#define O1S 68   // out1 slice n-stride in dwords (64 + 4 pad)

typedef short bf16x8 __attribute__((ext_vector_type(8)));
typedef float f32x16 __attribute__((ext_vector_type(16)));
typedef float f32x4 __attribute__((ext_vector_type(4)));
typedef unsigned short u16x4 __attribute__((ext_vector_type(4)));

__device__ __forceinline__ unsigned short f2bf(float f) {
    unsigned int u = __builtin_bit_cast(unsigned int, f);
    u = (u + 0x7fffu + ((u >> 16) & 1u)) >> 16;   // RNE
    return (unsigned short)u;
}

// --- prep: proto fp32 -> bf16 MFMA-fragment layout + proto_sq fp32 ---
// Fragment word (16B) at ((tile*16 + kk)*64 + fl)*8 holds
//   B[p = tile*32 + (fl&31)][k = kk*16 + (fl>>5)*8 + 0..7]
// i.e. exactly the bf16x8 the 32x32x16 MFMA B-operand wants from lane fl.
__global__ __launch_bounds__(256) void proto_prep(const float* __restrict__ proto,
                                                  unsigned short* __restrict__ bwf,
                                                  float* __restrict__ psq) {
    const int w = threadIdx.x >> 6, lane = threadIdx.x & 63;
    const int l31 = lane & 31, hf = lane >> 5;
    const int row = blockIdx.x * 8 + w * 2 + hf;        // 64 blocks * 8 rows
    const int oct = l31;                                // k-octet 0..31
    const float* src = proto + (size_t)row * DD + oct * 8;
    const f32x4 f0 = *(const f32x4*)(src);
    const f32x4 f1 = *(const f32x4*)(src + 4);
    bf16x8 b;
    b[0] = (short)f2bf(f0.x); b[1] = (short)f2bf(f0.y);
    b[2] = (short)f2bf(f0.z); b[3] = (short)f2bf(f0.w);
    b[4] = (short)f2bf(f1.x); b[5] = (short)f2bf(f1.y);
    b[6] = (short)f2bf(f1.z); b[7] = (short)f2bf(f1.w);
    const int tile = row >> 5;
    const int kk = oct >> 1;
    const int fl = ((oct & 1) << 5) | (row & 31);
    *(bf16x8*)(bwf + ((size_t)(tile * 16 + kk) * 64 + fl) * 8) = b;

    float part = f0.x * f0.x + f0.y * f0.y + f0.z * f0.z + f0.w * f0.w
               + f1.x * f1.x + f1.y * f1.y + f1.z * f1.z + f1.w * f1.w;
    // reduce across the 32-lane half (offsets < 32 stay within the half)
    #pragma unroll
    for (int o = 16; o > 0; o >>= 1) part += __shfl_xor(part, o, 64);
    if (l31 == 0) psq[row] = part;
}

// --- main: block = 8 waves, 64 feature rows x all 512 prototypes ---
__global__ __launch_bounds__(512, 4) void proto_dist(
        const float* __restrict__ feat,
        const unsigned short* __restrict__ bw,
        const float* __restrict__ psq,
        float* __restrict__ out0,   // [N][512]
        float* __restrict__ out1,   // [512][N]
        int N) {
    // union region: phase 1 A-slab 64x280 bf16 (35840B);
    //               phase 2 out0 slice [32][512] f32 (65536B)  <- max
    //               phase 3 out1 slice [128][68] f32 (34816B)
    __shared__ unsigned char S[65536];
    __shared__ float fsq[BN];
    unsigned short* A_lds = (unsigned short*)S;
    float* lds_f = (float*)S;

    const int tid = threadIdx.x;
    const int w = tid >> 6, lane = tid & 63;
    const int n0 = blockIdx.x * BN;

    // stage A: fp32 global -> bf16 LDS (coalesced; feat read exactly once)
    #pragma unroll
    for (int i = 0; i < 8; ++i) {
        const int row = i * 8 + w;
        const f32x4 f = __builtin_nontemporal_load(
            (const f32x4*)(feat + (size_t)(n0 + row) * DD + lane * 4));
        u16x4 u;
        u.x = f2bf(f.x); u.y = f2bf(f.y); u.z = f2bf(f.z); u.w = f2bf(f.w);
        *(u16x4*)&A_lds[row * AP + lane * 4] = u;
        float part = f.x * f.x + f.y * f.y + f.z * f.z + f.w * f.w;
        for (int o = 32; o > 0; o >>= 1) part += __shfl_xor(part, o, 64);
        if (lane == 0) fsq[row] = part;
    }
    __syncthreads();

    const int r = w & 1;            // n-tile (32 rows)
    const int g = w >> 1;           // p-group (128 cols)
    const int colT = g * 128;
    const int l31 = lane & 31;
    const int hi = lane >> 5;

    // A operand: A[m = lane&31][k = (lane>>5)*8 + j]
    const unsigned short* arow = &A_lds[(32 * r + l31) * AP + hi * 8];
    // B fragments for this wave's 4 tiles: base + (t*16 + kk)*512 + lane*8
    const unsigned short* bwf_w = bw + (size_t)g * 4 * 16 * 512;

    f32x16 acc[4];
    #pragma unroll
    for (int t = 0; t < 4; ++t)
        #pragma unroll
        for (int e = 0; e < 16; ++e) acc[t][e] = 0.0f;

    #pragma unroll 2
    for (int kk = 0; kk < 16; ++kk) {
        const bf16x8 a = *(const bf16x8*)(arow + kk * 16);
        #pragma unroll
        for (int t = 0; t < 4; ++t) {
            const bf16x8 b = *(const bf16x8*)(bwf_w + ((t * 16 + kk) * 64 + lane) * 8);
            acc[t] = __builtin_amdgcn_mfma_f32_32x32x16_bf16(a, b, acc[t], 0, 0, 0);
        }
    }

    // per-lane epilogue constants (fsq is its own LDS array, safe to read)
    f32x4 fsq_q[4];
    #pragma unroll
    for (int q = 0; q < 4; ++q)
        fsq_q[q] = *(const f32x4*)&fsq[32 * r + 8 * q + 4 * hi];
    f32x4 psqv;
    #pragma unroll
    for (int t = 0; t < 4; ++t) psqv[t] = psq[colT + 32 * t + l31];

    __syncthreads();   // all waves done reading A_lds; reuse region

    // ---- out0: two slices of [32 n][512 p], stores 1KB/instr ----
    #pragma unroll
    for (int s = 0; s < 2; ++s) {
        if (r == s) {
            // C/D layout (m74/m101): col=lane&31 (p), row=(reg&3)+8*(reg>>2)+4*hi (n)
            #pragma unroll
            for (int t = 0; t < 4; ++t)
                #pragma unroll
                for (int q = 0; q < 4; ++q)
                    #pragma unroll
                    for (int e = 0; e < 4; ++e) {
                        const int n_l = e + 8 * q + 4 * hi;
                        lds_f[n_l * 512 + colT + 32 * t + l31] =
                            fsq_q[q][e] + psqv[t] - 2.0f * acc[t][4 * q + e];
                    }
        }
        __syncthreads();
        float* o0 = out0 + (size_t)(n0 + 32 * s) * PP;
        const int row = tid >> 7;              // 0..3
        const int off = (tid & 127) * 4;       // 0..508
        #pragma unroll
        for (int rr = 0; rr < 8; ++rr) {
            const f32x4 v = *(const f32x4*)&lds_f[(row + 4 * rr) * 512 + off];
            __builtin_nontemporal_store(
                v, (f32x4*)(o0 + (size_t)(row + 4 * rr) * PP + off));
        }
        __syncthreads();
    }

    // ---- out1: four slices of [128 p][64 n] (stride 68), stores 256B runs ----
    #pragma unroll
    for (int sp = 0; sp < 4; ++sp) {
        if (g == sp) {
            #pragma unroll
            for (int t = 0; t < 4; ++t) {
                const int p_loc = 32 * t + l31;
                #pragma unroll
                for (int q = 0; q < 4; ++q) {
                    f32x4 d;
                    #pragma unroll
                    for (int e = 0; e < 4; ++e)
                        d[e] = fsq_q[q][e] + psqv[t] - 2.0f * acc[t][4 * q + e];
                    // n = 32r + e+8q+4hi: quad over e is 4 consecutive n
                    *(f32x4*)&lds_f[p_loc * O1S + 32 * r + 8 * q + 4 * hi] = d;
                }
            }
        }
        __syncthreads();
        const int p_row = tid >> 4;            // 0..31
        const int n_off = (tid & 15) * 4;      // 0..60
        float* o1 = out1 + (size_t)(128 * sp) * N + n0;
        #pragma unroll
        for (int rr = 0; rr < 4; ++rr) {
            const f32x4 v = *(const f32x4*)&lds_f[(p_row + 32 * rr) * O1S + n_off];
            __builtin_nontemporal_store(
                v, (f32x4*)(o1 + (size_t)(p_row + 32 * rr) * N + n_off));
        }
        if (sp < 3) __syncthreads();
    }
}

extern "C" void kernel_launch(void* const* d_in, const int* in_sizes, int n_in,
                              void* d_out, int out_size, void* d_ws, size_t ws_size,
                              hipStream_t stream) {
    const float* feat = (const float*)d_in[0];
    const float* proto = (const float*)d_in[1];
    const int N = in_sizes[0] / DD;          // 65536

    unsigned short* bw = (unsigned short*)d_ws;                // 512*256*2 = 256 KB
    float* psq = (float*)((char*)d_ws + (size_t)PP * DD * 2);  // +2 KB

    float* out0 = (float*)d_out;
    float* out1 = out0 + (size_t)N * PP;

    proto_prep<<<PP / 8, 256, 0, stream>>>(proto, bw, psq);
    proto_dist<<<N / BN, 512, 0, stream>>>(feat, bw, psq, out0, out1, N);
}

// Round 7
// 320.466 us; speedup vs baseline: 1.2024x; 1.0192x over previous
//
#include <hip/hip_runtime.h>
#include <hip/hip_bf16.h>

// ProtoLayer: dists_to_protos[n][p] = |f_n|^2 + |p_p|^2 - 2 f_n.p_p  (N x P)
//             dists_to_latents      = transpose of the above          (P x N)
// N=65536, P=512, D=256, fp32 in/out. Memory-bound (~332 MB traffic, floor ~53us).
// R8: barrier-free epilogue on top of R7b's pre-swizzled-B win (357->327).
//     dist ~154us vs 53us floor; R7b's cooperative epilogue had 11 syncthreads,
//     each draining the full nontemporal store queue (s_waitcnt vmcnt(0) before
//     s_barrier) -> burst/drain serialization. Replace with R3's proven
//     epilogue: direct scalar out0 stores from acc (128B segments; R3==R6
//     exonerated short store runs), per-wave-private 32x36 LDS transpose for
//     out1 (same-wave exchange, lgkmcnt-ordered, no barrier). A-slab and
//     transpose tiles in DISJOINT LDS (72.9KB, still 2 blocks/CU: VGPR-capped)
//     so the post-K barrier disappears too. Exactly ONE __syncthreads (after
//     staging, before any stores exist). K-loop + prep identical to R7b.

#define DD 256
#define PP 512
#define BN 64
#define AP 280   // A slab row stride in bf16 elems (256 + 24 pad)
#define TP 36    // transpose tile n-stride in dwords (32 + 4; *4B = 144, 16B-aligned)

typedef short bf16x8 __attribute__((ext_vector_type(8)));
typedef float f32x16 __attribute__((ext_vector_type(16)));
typedef float f32x4 __attribute__((ext_vector_type(4)));
typedef unsigned short u16x4 __attribute__((ext_vector_type(4)));

__device__ __forceinline__ unsigned short f2bf(float f) {
    unsigned int u = __builtin_bit_cast(unsigned int, f);
    u = (u + 0x7fffu + ((u >> 16) & 1u)) >> 16;   // RNE
    return (unsigned short)u;
}

// --- prep: proto fp32 -> bf16 MFMA-fragment layout + proto_sq fp32 ---
// Fragment word (16B) at ((tile*16 + kk)*64 + fl)*8 holds
//   B[p = tile*32 + (fl&31)][k = kk*16 + (fl>>5)*8 + 0..7]
// i.e. exactly the bf16x8 the 32x32x16 MFMA B-operand wants from lane fl.
__global__ __launch_bounds__(256) void proto_prep(const float* __restrict__ proto,
                                                  unsigned short* __restrict__ bwf,
                                                  float* __restrict__ psq) {
    const int w = threadIdx.x >> 6, lane = threadIdx.x & 63;
    const int l31 = lane & 31, hf = lane >> 5;
    const int row = blockIdx.x * 8 + w * 2 + hf;        // 64 blocks * 8 rows
    const int oct = l31;                                // k-octet 0..31
    const float* src = proto + (size_t)row * DD + oct * 8;
    const f32x4 f0 = *(const f32x4*)(src);
    const f32x4 f1 = *(const f32x4*)(src + 4);
    bf16x8 b;
    b[0] = (short)f2bf(f0.x); b[1] = (short)f2bf(f0.y);
    b[2] = (short)f2bf(f0.z); b[3] = (short)f2bf(f0.w);
    b[4] = (short)f2bf(f1.x); b[5] = (short)f2bf(f1.y);
    b[6] = (short)f2bf(f1.z); b[7] = (short)f2bf(f1.w);
    const int tile = row >> 5;
    const int kk = oct >> 1;
    const int fl = ((oct & 1) << 5) | (row & 31);
    *(bf16x8*)(bwf + ((size_t)(tile * 16 + kk) * 64 + fl) * 8) = b;

    float part = f0.x * f0.x + f0.y * f0.y + f0.z * f0.z + f0.w * f0.w
               + f1.x * f1.x + f1.y * f1.y + f1.z * f1.z + f1.w * f1.w;
    // reduce across the 32-lane half (offsets < 32 stay within the half)
    #pragma unroll
    for (int o = 16; o > 0; o >>= 1) part += __shfl_xor(part, o, 64);
    if (l31 == 0) psq[row] = part;
}

// --- main: block = 8 waves, 64 feature rows x all 512 prototypes ---
__global__ __launch_bounds__(512, 4) void proto_dist(
        const float* __restrict__ feat,
        const unsigned short* __restrict__ bw,
        const float* __restrict__ psq,
        float* __restrict__ out0,   // [N][512]
        float* __restrict__ out1,   // [512][N]
        int N) {
    __shared__ unsigned short A_lds[BN * AP];           // 35840 B
    __shared__ float Strans[8 * 32 * TP];               // 36864 B (per-wave tiles)
    __shared__ float fsq[BN];

    const int tid = threadIdx.x;
    const int w = tid >> 6, lane = tid & 63;
    const int n0 = blockIdx.x * BN;

    // stage A: fp32 global -> bf16 LDS (coalesced; feat read exactly once)
    #pragma unroll
    for (int i = 0; i < 8; ++i) {
        const int row = i * 8 + w;
        const f32x4 f = __builtin_nontemporal_load(
            (const f32x4*)(feat + (size_t)(n0 + row) * DD + lane * 4));
        u16x4 u;
        u.x = f2bf(f.x); u.y = f2bf(f.y); u.z = f2bf(f.z); u.w = f2bf(f.w);
        *(u16x4*)&A_lds[row * AP + lane * 4] = u;
        float part = f.x * f.x + f.y * f.y + f.z * f.z + f.w * f.w;
        for (int o = 32; o > 0; o >>= 1) part += __shfl_xor(part, o, 64);
        if (lane == 0) fsq[row] = part;
    }
    __syncthreads();   // the ONLY barrier in this kernel

    const int r = w & 1;            // n-tile (32 rows)
    const int g = w >> 1;           // p-group (128 cols)
    const int colT = g * 128;
    const int l31 = lane & 31;
    const int hi = lane >> 5;

    // A operand: A[m = lane&31][k = (lane>>5)*8 + j]
    const unsigned short* arow = &A_lds[(32 * r + l31) * AP + hi * 8];
    // B fragments for this wave's 4 tiles: base + (t*16 + kk)*512 + lane*8
    const unsigned short* bwf_w = bw + (size_t)g * 4 * 16 * 512;

    f32x16 acc[4];
    #pragma unroll
    for (int t = 0; t < 4; ++t)
        #pragma unroll
        for (int e = 0; e < 16; ++e) acc[t][e] = 0.0f;

    #pragma unroll 2
    for (int kk = 0; kk < 16; ++kk) {
        const bf16x8 a = *(const bf16x8*)(arow + kk * 16);
        #pragma unroll
        for (int t = 0; t < 4; ++t) {
            const bf16x8 b = *(const bf16x8*)(bwf_w + ((t * 16 + kk) * 64 + lane) * 8);
            acc[t] = __builtin_amdgcn_mfma_f32_32x32x16_bf16(a, b, acc[t], 0, 0, 0);
        }
    }

    // per-lane epilogue constants (fsq written pre-barrier; ordered)
    f32x4 fsq_q[4];
    #pragma unroll
    for (int q = 0; q < 4; ++q)
        fsq_q[q] = *(const f32x4*)&fsq[32 * r + 8 * q + 4 * hi];

    float* trans = Strans + w * (32 * TP);   // per-wave private 32x36 fp32
    float* out0_base = out0 + (size_t)(n0 + 32 * r) * PP;

    #pragma unroll
    for (int t = 0; t < 4; ++t) {
        const int p = colT + 32 * t + l31;
        const float psq_v = psq[p];
        // C/D layout (m74/m101): col=lane&31 (p), row=(reg&3)+8*(reg>>2)+4*hi (n)
        #pragma unroll
        for (int q = 0; q < 4; ++q) {
            f32x4 d;
            #pragma unroll
            for (int e = 0; e < 4; ++e) {
                const int n_l = e + 8 * q + 4 * hi;
                const float dist = fsq_q[q][e] + psq_v - 2.0f * acc[t][4 * q + e];
                d[e] = dist;
                __builtin_nontemporal_store(dist, out0_base + (size_t)n_l * PP + p);
            }
            // p-major transpose tile: row = p-local (l31), 4 consecutive n
            *(f32x4*)&trans[l31 * TP + 8 * q + 4 * hi] = d;
        }
        // same-wave LDS exchange (in-order DS per wave; lgkmcnt auto-inserted)
        #pragma unroll
        for (int j = 0; j < 4; ++j) {
            const int p_row = j * 8 + (lane >> 3);       // 8 p-rows per instr
            const int n_off = (lane & 7) * 4;            // 8 lanes * 4 n = 32 n
            const f32x4 v = *(const f32x4*)&trans[p_row * TP + n_off];
            __builtin_nontemporal_store(v,
                (f32x4*)(out1 + (size_t)(colT + 32 * t + p_row) * N
                               + (n0 + 32 * r + n_off)));
        }
    }
}

extern "C" void kernel_launch(void* const* d_in, const int* in_sizes, int n_in,
                              void* d_out, int out_size, void* d_ws, size_t ws_size,
                              hipStream_t stream) {
    const float* feat = (const float*)d_in[0];
    const float* proto = (const float*)d_in[1];
    const int N = in_sizes[0] / DD;          // 65536

    unsigned short* bw = (unsigned short*)d_ws;                // 512*256*2 = 256 KB
    float* psq = (float*)((char*)d_ws + (size_t)PP * DD * 2);  // +2 KB

    float* out0 = (float*)d_out;
    float* out1 = out0 + (size_t)N * PP;

    proto_prep<<<PP / 8, 256, 0, stream>>>(proto, bw, psq);
    proto_dist<<<N / BN, 512, 0, stream>>>(feat, bw, psq, out0, out1, N);
}